// Round 12
// baseline (251.074 us; speedup 1.0000x reference)
//
#include <hip/hip_runtime.h>
#include <stdint.h>

typedef __bf16 bf16_t;
typedef bf16_t bf16x8 __attribute__((ext_vector_type(8)));
typedef float  f32x4  __attribute__((ext_vector_type(4)));
typedef float  f32x2v __attribute__((ext_vector_type(2)));

static constexpr uint32_t PRIME = 2654435761u;
static constexpr uint32_t HMASK = (1u << 17) - 1u;   // HASHMAP_SIZE - 1
static constexpr uint32_t TSIZE = 1u << 17;

// dense mini-grid geometry, levels 0..7 (scale_l = 16*1.5^l, W = ceil(scale)+1)
static constexpr int NDALL  = 136642;   // lv0..7: 17^2+25^2+37^2+55^2+82^2+123^2+184^2+275^2

// features stored as fp8-e4m3 pairs, pre-scaled by 2^13 (|f|<=1e-4 -> +-0.82).
// un-scale 2^-13 is folded into the layer-0 weight fragments.
static constexpr float FSCALE = 8192.0f;        // 2^13
static constexpr float WSCALE = 1.0f / 8192.0f; // 2^-13

__device__ __forceinline__ uint32_t fbits(float f) {
    union { float f; uint32_t u; } v; v.f = f; return v.u;
}
__device__ __forceinline__ float asfloat(uint32_t u) {
    union { uint32_t u; float f; } v; v.u = u; return v.f;
}
__device__ __forceinline__ uint32_t bf16bits(float f) {
    union { bf16_t h; uint16_t u; } v; v.h = (bf16_t)f; return (uint32_t)v.u;
}

// ---- fp8 pair encode/decode (OCP e4m3fn). HW path on gfx950, manual fallback.
__device__ __forceinline__ uint32_t enc8(float v) {   // manual e4m3fn RNE
    const uint32_t s = (fbits(v) >> 24) & 0x80u;
    float m = fabsf(v) * 0x1p-120f;                   // map e4m3 grid onto fp32 bits
    uint32_t u = fbits(m);
    u += 0x7FFFFu + ((u >> 20) & 1u);                 // RNE at bit 20
    return s | ((u >> 20) & 0x7fu);
}
__device__ __forceinline__ uint32_t pack8(float a, float b) {
#if __has_builtin(__builtin_amdgcn_cvt_pk_fp8_f32)
    return (uint32_t)__builtin_amdgcn_cvt_pk_fp8_f32(a, b, 0, false) & 0xffffu;
#else
    return enc8(a) | (enc8(b) << 8);
#endif
}
__device__ __forceinline__ float2 unpack8(uint32_t u) {
#if __has_builtin(__builtin_amdgcn_cvt_pk_f32_fp8)
    f32x2v r = __builtin_amdgcn_cvt_pk_f32_fp8((int)(u & 0xffffu), false);
    return make_float2(r.x, r.y);
#else
    const float f0 = asfloat(((u & 0x80u) << 24) | ((u & 0x7fu) << 20)) * 0x1p120f;
    const float f1 = asfloat(((u & 0x8000u) << 16) | ((u & 0x7f00u) << 12)) * 0x1p120f;
    return make_float2(f0, f1);
#endif
}

// ---- prepass A: repack levels 8..15 of fp32 [T][L][F] -> fp8-pair ushorts,
// level-major [l-8][T] (2 MB). LDS-tiled transpose, coalesced writes.
__global__ __launch_bounds__(256)
void repack_enc8(const float2* __restrict__ src, uint16_t* __restrict__ dst) {
    __shared__ uint16_t ldsT[8 * 257];      // [l8][t_local], +1 pad
    const int tid = threadIdx.x;
    const int t0  = blockIdx.x * 256;       // 512 blocks x 256 t-entries
#pragma unroll
    for (int k = 0; k < 8; ++k) {
        const int j = k * 256 + tid;        // (t_local, l8): l8 fastest
        const int tl = j >> 3, l8 = j & 7;
        const float2 f = src[((size_t)(t0 + tl) << 4) + 8 + l8];
        ldsT[l8 * 257 + tl] = (uint16_t)pack8(f.x * FSCALE, f.y * FSCALE);
    }
    __syncthreads();
#pragma unroll
    for (int k = 0; k < 8; ++k)
        dst[((uint32_t)k << 17) + t0 + tid] = ldsT[k * 257 + tid];
}

// ---- prepass B: dense mini-grids, levels 0..7 (267 KB, fp8-pair ushorts).
__global__ __launch_bounds__(256)
void densify_enc(const float2* __restrict__ src, uint16_t* __restrict__ dst) {
    const int i = blockIdx.x * 256 + threadIdx.x;
    if (i >= NDALL) return;
    int lvl, W, off;
    if      (i <   289) { lvl = 0; W =  17; off = 0;     }
    else if (i <   914) { lvl = 1; W =  25; off = 289;   }
    else if (i <  2283) { lvl = 2; W =  37; off = 914;   }
    else if (i <  5308) { lvl = 3; W =  55; off = 2283;  }
    else if (i < 12032) { lvl = 4; W =  82; off = 5308;  }
    else if (i < 27161) { lvl = 5; W = 123; off = 12032; }
    else if (i < 61017) { lvl = 6; W = 184; off = 27161; }
    else                { lvl = 7; W = 275; off = 61017; }
    const int li = i - off;
    const uint32_t iy = (uint32_t)(li / W), ix = (uint32_t)(li % W);
    const uint32_t h = (ix ^ (iy * PRIME)) & HMASK;
    const float2 f = src[h * 16 + lvl];
    dst[i] = (uint16_t)pack8(f.x * FSCALE, f.y * FSCALE);
}

// ---- prepass C: overlapping pairs pair[i] = (d16[i], d16[i+1]) -> one dword
// load covers both x-corners of a dense bilerp (branch-free extract).
__global__ __launch_bounds__(256)
void pairify_enc(const uint16_t* __restrict__ d16, uint32_t* __restrict__ dst) {
    const int i = blockIdx.x * 256 + threadIdx.x;
    if (i >= NDALL) return;
    const uint32_t a = d16[i];
    const uint32_t b = (i + 1 < NDALL) ? d16[i + 1] : 0u;
    dst[i] = a | (b << 16);
}

// R12: wave-specialized encode. Block = 64 points (4 tiles). Phase A: wave w
// computes levels 4w..4w+3 for ALL 64 points (lane = point) -> every gather
// path is WAVE-UNIFORM (no exec-mask triple-issue): w0 dense pairs lv0..3
// (L1-hot), w1 dense pairs lv4..7 (L2), w2/w3 hashed lv8..15 (4 independent
// plain loads each -- R9/R10 lesson). Feats land in a double-buffered LDS
// tile feat[j][p] (stride-65: conflict-free writes, <=4-way read conflicts).
// Phase B: wave w MFMAs tile w exactly as R8 (q=lane>>4, n16=lane&15,
// A[m=n16][k=q*8+j]). Pipeline: iteration i+1's gathers issue BEFORE B(i)'s
// MFMAs -- landing zone is LDS so only one 16-reg gather set is live
// (launch_bounds(256,2): 256-VGPR headroom, no R10 spill mechanism).
__global__ __launch_bounds__(256, 2)
void fused_hash_mlp(const float* __restrict__ xin,
                    const uint16_t* __restrict__ tab8,   // hashed lv8..15, fp8
                    const uint32_t* __restrict__ dpair,  // dense lv0..7, pairs
                    const float* __restrict__ w0, const float* __restrict__ b0,
                    const float* __restrict__ w1, const float* __restrict__ b1,
                    const float* __restrict__ w2, const float* __restrict__ b2,
                    float* __restrict__ out,
                    int nGroups)
{
    __shared__ __align__(16) uint32_t feat[2][16 * 65];  // 8320 B (j*65+p)
    __shared__ __align__(16) bf16_t lds[4 * 16 * 80];    // 10240 B per-wave tiles

    const int tid  = threadIdx.x;
    const int wib  = tid >> 6;      // phase A: level-quad; phase B: tile
    const int lane = tid & 63;
    const int q    = lane >> 4;
    const int n16  = lane & 15;
    const int lq   = wib;           // level-quad handled in phase A
    const int p    = lane;          // point index in phase A

    bf16_t* myLds = &lds[wib * (16 * 80)];

    // ---- weight B-fragments (fp32 -> bf16 once). Bw0 absorbs the 2^-13
    // feature un-scale (A carries feat*2^13).
    bf16x8 Bw0[4], Bw1[2][4], Bw2[2];
#pragma unroll
    for (int t = 0; t < 4; ++t)
#pragma unroll
        for (int j = 0; j < 8; ++j)
            Bw0[t][j] = (bf16_t)(w0[(q * 8 + j) * 64 + t * 16 + n16] * WSCALE);
#pragma unroll
    for (int c = 0; c < 2; ++c)
#pragma unroll
        for (int t = 0; t < 4; ++t)
#pragma unroll
            for (int j = 0; j < 8; ++j)
                Bw1[c][t][j] = (bf16_t)w1[(c * 32 + q * 8 + j) * 64 + t * 16 + n16];
#pragma unroll
    for (int c = 0; c < 2; ++c)
#pragma unroll
        for (int j = 0; j < 8; ++j)
            Bw2[c][j] = (n16 < 3) ? (bf16_t)w2[(c * 32 + q * 8 + j) * 3 + n16]
                                  : (bf16_t)0.0f;

    float bv0[4], bv1[4];
#pragma unroll
    for (int t = 0; t < 4; ++t) {
        bv0[t] = b0[t * 16 + n16];
        bv1[t] = b1[t * 16 + n16];
    }
    const float bv2 = (n16 < 3) ? b2[n16] : 0.0f;

    // phase-A scales (wave-uniform): levels 4*lq .. 4*lq+3; exact fp32.
    const float sbA = 16.0f * ((lq == 0) ? 1.0f :
                               (lq == 1) ? 5.0625f :
                               (lq == 2) ? 25.62890625f :
                                           129.746337890625f);
    const float scA[4] = { sbA, sbA * 1.5f, sbA * 2.25f, sbA * 3.375f };

    // hashed sub-table base for lq>=2 (wave-uniform)
    const uint32_t l8base = ((uint32_t)((lq >= 2 ? lq - 2 : 0) * 4)) << 17;

    // phase A: gather (issue only; results in u)
    auto gatherA = [&](int gg, uint32_t (&u)[4][4], float2& xy) {
        xy = ((const float2*)xin)[gg * 64 + p];
#pragma unroll
        for (int lv = 0; lv < 4; ++lv) {
            const uint32_t ix = (uint32_t)floorf(xy.x * scA[lv]);
            const uint32_t iy = (uint32_t)floorf(xy.y * scA[lv]);
            // dense geometry (compile-time under unroll; selected per wave)
            const uint32_t Wl = (lv == 0) ? 17u  : (lv == 1) ? 25u
                              : (lv == 2) ? 37u  : 55u;
            const uint32_t Ol = (lv == 0) ? 0u   : (lv == 1) ? 289u
                              : (lv == 2) ? 914u : 2283u;
            const uint32_t Wg = (lv == 0) ? 82u    : (lv == 1) ? 123u
                              : (lv == 2) ? 184u   : 275u;
            const uint32_t Og = (lv == 0) ? 5308u  : (lv == 1) ? 12032u
                              : (lv == 2) ? 27161u : 61017u;
            if (lq == 0) {           // lv 0..3: dense pairs (L1-hot, 21 KB)
                const uint32_t a = Ol + iy * Wl + ix;
                u[lv][0] = dpair[a];
                u[lv][1] = dpair[a + Wl];
            } else if (lq == 1) {    // lv 4..7: dense pairs (L2)
                const uint32_t a = Og + iy * Wg + ix;
                u[lv][0] = dpair[a];
                u[lv][1] = dpair[a + Wg];
            } else {                 // lv 8..15: hashed, 4 independent loads
                const uint32_t hy0 = iy * PRIME, hy1 = hy0 + PRIME;
                const uint32_t base = l8base + ((uint32_t)lv << 17);
                u[lv][0] = tab8[base + (( ix       ^ hy0) & HMASK)];
                u[lv][1] = tab8[base + (((ix + 1u) ^ hy0) & HMASK)];
                u[lv][2] = tab8[base + (( ix       ^ hy1) & HMASK)];
                u[lv][3] = tab8[base + (((ix + 1u) ^ hy1) & HMASK)];
            }
        }
    };

    // phase A: bilerp + write feat buffer
    auto bilerpWrite = [&](int buf, const float2 xy, const uint32_t (&u)[4][4]) {
#pragma unroll
        for (int lv = 0; lv < 4; ++lv) {
            const float posx = xy.x * scA[lv], posy = xy.y * scA[lv];
            const float frx = posx - floorf(posx);
            const float fry = posy - floorf(posy);
            float2 e00, e10, e01, e11;
            if (lq <= 1) {           // pair dwords: (x, x+1) in lo/hi ushort
                e00 = unpack8(u[lv][0] & 0xffffu);
                e10 = unpack8(u[lv][0] >> 16);
                e01 = unpack8(u[lv][1] & 0xffffu);
                e11 = unpack8(u[lv][1] >> 16);
            } else {
                e00 = unpack8(u[lv][0]);
                e10 = unpack8(u[lv][1]);
                e01 = unpack8(u[lv][2]);
                e11 = unpack8(u[lv][3]);
            }
            const float wx1 = frx, wx0 = 1.0f - frx, wy1 = fry, wy0 = 1.0f - fry;
            const float w00 = wx0 * wy0, w10 = wx1 * wy0, w01 = wx0 * wy1, w11 = wx1 * wy1;
            const float f0 = w00 * e00.x + w10 * e10.x + w01 * e01.x + w11 * e11.x;
            const float f1 = w00 * e00.y + w10 * e10.y + w01 * e01.y + w11 * e11.y;
            feat[buf][(lq * 4 + lv) * 65 + p] = bf16bits(f0) | (bf16bits(f1) << 16);
        }
    };

    // phase B: MLP for tile wib of group gg, feats from feat[buf]
    auto processB = [&](int gg, int buf) {
        union { uint32_t u[4]; bf16x8 v; } afu;
#pragma unroll
        for (int r = 0; r < 4; ++r)
            afu.u[r] = feat[buf][(q * 4 + r) * 65 + wib * 16 + n16];
        const bf16x8 af = afu.v;

        f32x4 c0[4];
#pragma unroll
        for (int t = 0; t < 4; ++t) {
            f32x4 cc = { bv0[t], bv0[t], bv0[t], bv0[t] };
            c0[t] = __builtin_amdgcn_mfma_f32_16x16x32_bf16(af, Bw0[t], cc, 0, 0, 0);
        }
#pragma unroll
        for (int t = 0; t < 4; ++t)
#pragma unroll
            for (int r = 0; r < 4; ++r)
                myLds[(q * 4 + r) * 80 + t * 16 + n16] = (bf16_t)fmaxf(c0[t][r], 0.0f);
        bf16x8 A1[2];
#pragma unroll
        for (int c = 0; c < 2; ++c)
            A1[c] = *(const bf16x8*)&myLds[n16 * 80 + c * 32 + q * 8];

        f32x4 c1[4];
#pragma unroll
        for (int t = 0; t < 4; ++t) {
            f32x4 cc = { bv1[t], bv1[t], bv1[t], bv1[t] };
            cc    = __builtin_amdgcn_mfma_f32_16x16x32_bf16(A1[0], Bw1[0][t], cc, 0, 0, 0);
            c1[t] = __builtin_amdgcn_mfma_f32_16x16x32_bf16(A1[1], Bw1[1][t], cc, 0, 0, 0);
        }
#pragma unroll
        for (int t = 0; t < 4; ++t)
#pragma unroll
            for (int r = 0; r < 4; ++r)
                myLds[(q * 4 + r) * 80 + t * 16 + n16] = (bf16_t)fmaxf(c1[t][r], 0.0f);
        bf16x8 A2[2];
#pragma unroll
        for (int c = 0; c < 2; ++c)
            A2[c] = *(const bf16x8*)&myLds[n16 * 80 + c * 32 + q * 8];

        f32x4 co = { bv2, bv2, bv2, bv2 };
        co = __builtin_amdgcn_mfma_f32_16x16x32_bf16(A2[0], Bw2[0], co, 0, 0, 0);
        co = __builtin_amdgcn_mfma_f32_16x16x32_bf16(A2[1], Bw2[1], co, 0, 0, 0);

        const int tile = gg * 4 + wib;
        if (n16 < 3) {
#pragma unroll
            for (int r = 0; r < 4; ++r)
                out[(size_t)(tile * 16 + q * 4 + r) * 3 + n16] = co[r];
        }
    };

    // ---- pipelined main loop: 1 barrier/iter, feat double-buffered ----
    const int stride = gridDim.x;
    int g = blockIdx.x;
    if (g >= nGroups) return;

    uint32_t u[4][4];
    float2 xy;
    gatherA(g, u, xy);
    bilerpWrite(0, xy, u);
    __syncthreads();

    int it = 0;
    int gPrev = g;
    for (g += stride; g < nGroups; g += stride) {
        uint32_t u2[4][4];
        float2 xy2;
        gatherA(g, u2, xy2);            // loads in flight across B below
        processB(gPrev, it & 1);        // MFMA on previous group's feats
        bilerpWrite((it + 1) & 1, xy2, u2);
        __syncthreads();
        gPrev = g;
        ++it;
    }
    processB(gPrev, it & 1);
}

// ---- fallback (R2 known-good): direct fp32 gather, used only if ws too small
__global__ __launch_bounds__(256)
void fused_hash_mlp_fp32(const float* __restrict__ xin,
                         const float* __restrict__ enc,
                         const float* __restrict__ w0, const float* __restrict__ b0,
                         const float* __restrict__ w1, const float* __restrict__ b1,
                         const float* __restrict__ w2, const float* __restrict__ b2,
                         float* __restrict__ out,
                         int nGroups)
{
    __shared__ __align__(16) bf16_t lds[4 * 16 * 80];
    const int tid  = threadIdx.x;
    const int wib  = tid >> 6;
    const int lane = tid & 63;
    const int q    = lane >> 4;
    const int n16  = lane & 15;
    bf16_t* myLds = &lds[wib * (16 * 80)];

    bf16x8 Bw0[4], Bw1[2][4], Bw2[2];
#pragma unroll
    for (int t = 0; t < 4; ++t)
#pragma unroll
        for (int j = 0; j < 8; ++j)
            Bw0[t][j] = (bf16_t)w0[(q * 8 + j) * 64 + t * 16 + n16];
#pragma unroll
    for (int c = 0; c < 2; ++c)
#pragma unroll
        for (int t = 0; t < 4; ++t)
#pragma unroll
            for (int j = 0; j < 8; ++j)
                Bw1[c][t][j] = (bf16_t)w1[(c * 32 + q * 8 + j) * 64 + t * 16 + n16];
#pragma unroll
    for (int c = 0; c < 2; ++c)
#pragma unroll
        for (int j = 0; j < 8; ++j)
            Bw2[c][j] = (n16 < 3) ? (bf16_t)w2[(c * 32 + q * 8 + j) * 3 + n16]
                                  : (bf16_t)0.0f;

    float bv0[4], bv1[4];
#pragma unroll
    for (int t = 0; t < 4; ++t) { bv0[t] = b0[t * 16 + n16]; bv1[t] = b1[t * 16 + n16]; }
    const float bv2 = (n16 < 3) ? b2[n16] : 0.0f;

    const float sb = 16.0f * ((q == 0) ? 1.0f : (q == 1) ? 5.0625f :
                              (q == 2) ? 25.62890625f : 129.746337890625f);
    const float sc[4] = { sb, sb * 1.5f, sb * 2.25f, sb * 3.375f };
    const char* encB = (const char*)enc;
    const uint32_t lvBase = (uint32_t)q * 32u;

    for (int g = blockIdx.x; g < nGroups; g += gridDim.x) {
        const int tile = g * 4 + wib;
        const int p = tile * 16 + n16;
        const float2 xy = ((const float2*)xin)[p];
        const float px = xy.x, py = xy.y;

        bf16x8 af;
#pragma unroll
        for (int lv = 0; lv < 4; ++lv) {
            const float posx = px * sc[lv], posy = py * sc[lv];
            const float fx = floorf(posx), fy = floorf(posy);
            const float frx = posx - fx,  fry = posy - fy;
            const uint32_t ix = (uint32_t)fx, iy = (uint32_t)fy;
            const uint32_t hy0 = iy * PRIME, hy1 = hy0 + PRIME;
            const uint32_t i00 = ( ix       ^ hy0) & HMASK;
            const uint32_t i10 = ((ix + 1u) ^ hy0) & HMASK;
            const uint32_t i01 = ( ix       ^ hy1) & HMASK;
            const uint32_t i11 = ((ix + 1u) ^ hy1) & HMASK;
            const uint32_t off = lvBase + (uint32_t)lv * 8u;
            const float2 e00 = *(const float2*)(encB + (i00 * 128u + off));
            const float2 e10 = *(const float2*)(encB + (i10 * 128u + off));
            const float2 e01 = *(const float2*)(encB + (i01 * 128u + off));
            const float2 e11 = *(const float2*)(encB + (i11 * 128u + off));
            const float wx1 = frx, wx0 = 1.0f - frx, wy1 = fry, wy0 = 1.0f - fry;
            const float w00 = wx0 * wy0, w10 = wx1 * wy0, w01 = wx0 * wy1, w11 = wx1 * wy1;
            af[2 * lv]     = (bf16_t)(w00 * e00.x + w10 * e10.x + w01 * e01.x + w11 * e11.x);
            af[2 * lv + 1] = (bf16_t)(w00 * e00.y + w10 * e10.y + w01 * e01.y + w11 * e11.y);
        }

        f32x4 c0[4];
#pragma unroll
        for (int t = 0; t < 4; ++t) {
            f32x4 cc = { bv0[t], bv0[t], bv0[t], bv0[t] };
            c0[t] = __builtin_amdgcn_mfma_f32_16x16x32_bf16(af, Bw0[t], cc, 0, 0, 0);
        }
        __syncthreads();
#pragma unroll
        for (int t = 0; t < 4; ++t)
#pragma unroll
            for (int r = 0; r < 4; ++r)
                myLds[(q * 4 + r) * 80 + t * 16 + n16] = (bf16_t)fmaxf(c0[t][r], 0.0f);
        __syncthreads();
        bf16x8 A1[2];
#pragma unroll
        for (int c = 0; c < 2; ++c)
            A1[c] = *(const bf16x8*)&myLds[n16 * 80 + c * 32 + q * 8];

        f32x4 c1[4];
#pragma unroll
        for (int t = 0; t < 4; ++t) {
            f32x4 cc = { bv1[t], bv1[t], bv1[t], bv1[t] };
            cc    = __builtin_amdgcn_mfma_f32_16x16x32_bf16(A1[0], Bw1[0][t], cc, 0, 0, 0);
            c1[t] = __builtin_amdgcn_mfma_f32_16x16x32_bf16(A1[1], Bw1[1][t], cc, 0, 0, 0);
        }
        __syncthreads();
#pragma unroll
        for (int t = 0; t < 4; ++t)
#pragma unroll
            for (int r = 0; r < 4; ++r)
                myLds[(q * 4 + r) * 80 + t * 16 + n16] = (bf16_t)fmaxf(c1[t][r], 0.0f);
        __syncthreads();
        bf16x8 A2[2];
#pragma unroll
        for (int c = 0; c < 2; ++c)
            A2[c] = *(const bf16x8*)&myLds[n16 * 80 + c * 32 + q * 8];

        f32x4 co = { bv2, bv2, bv2, bv2 };
        co = __builtin_amdgcn_mfma_f32_16x16x32_bf16(A2[0], Bw2[0], co, 0, 0, 0);
        co = __builtin_amdgcn_mfma_f32_16x16x32_bf16(A2[1], Bw2[1], co, 0, 0, 0);
        if (n16 < 3) {
#pragma unroll
            for (int r = 0; r < 4; ++r)
                out[(size_t)(tile * 16 + q * 4 + r) * 3 + n16] = co[r];
        }
    }
}

extern "C" void kernel_launch(void* const* d_in, const int* in_sizes, int n_in,
                              void* d_out, int out_size, void* d_ws, size_t ws_size,
                              hipStream_t stream) {
    const float* x  = (const float*)d_in[0];
    const float* en = (const float*)d_in[1];
    const float* w0 = (const float*)d_in[2];
    const float* b0 = (const float*)d_in[3];
    const float* w1 = (const float*)d_in[4];
    const float* b1 = (const float*)d_in[5];
    const float* w2 = (const float*)d_in[6];
    const float* b2 = (const float*)d_in[7];
    float* out = (float*)d_out;

    const int N = in_sizes[0] / 2;      // 2^20 points
    const int nTiles = N / 16;          // 65536
    const int nGroups = nTiles / 4;     // 16384 (64-point groups)

    // ws layout: tab8 (2 MB) | dpair (NDALL u32, 534 KB) | d16 scratch (267 KB)
    const size_t wsNeeded = (size_t)TSIZE * 8 * 2 + (size_t)NDALL * 4 + (size_t)NDALL * 2;
    if (ws_size >= wsNeeded) {
        uint16_t* tab8  = (uint16_t*)d_ws;
        uint32_t* dpair = (uint32_t*)(tab8 + (size_t)TSIZE * 8);
        uint16_t* d16   = (uint16_t*)(dpair + NDALL);
        repack_enc8<<<TSIZE / 256, 256, 0, stream>>>((const float2*)en, tab8);
        densify_enc<<<(NDALL + 255) / 256, 256, 0, stream>>>((const float2*)en, d16);
        pairify_enc<<<(NDALL + 255) / 256, 256, 0, stream>>>(d16, dpair);
        int blocks = 2048;
        if (blocks > nGroups) blocks = nGroups;
        fused_hash_mlp<<<blocks, 256, 0, stream>>>(x, tab8, dpair,
                                                   w0, b0, w1, b1, w2, b2, out, nGroups);
    } else {
        int blocks = 2048;
        if (blocks > nGroups) blocks = nGroups;
        fused_hash_mlp_fp32<<<blocks, 256, 0, stream>>>(x, en, w0, b0, w1, b1, w2, b2, out, nGroups);
    }
}

// Round 13
// 211.750 us; speedup vs baseline: 1.1857x; 1.1857x over previous
//
#include <hip/hip_runtime.h>
#include <stdint.h>

typedef __bf16 bf16_t;
typedef bf16_t bf16x8 __attribute__((ext_vector_type(8)));
typedef float  f32x4  __attribute__((ext_vector_type(4)));
typedef float  f32x2v __attribute__((ext_vector_type(2)));

static constexpr uint32_t PRIME = 2654435761u;
static constexpr uint32_t HMASK = (1u << 17) - 1u;   // HASHMAP_SIZE - 1
static constexpr uint32_t TSIZE = 1u << 17;

// dense mini-grid geometry, levels 0..7 (scale_l = 16*1.5^l, W = ceil(scale)+1)
static constexpr int NDALL  = 136642;   // 17^2+25^2+37^2+55^2+82^2+123^2+184^2+275^2

// features stored as fp8-e4m3 pairs, pre-scaled by 2^13 (|f|<=1e-4 -> +-0.82).
// un-scale 2^-13 is folded into the layer-0 weight fragments.
static constexpr float FSCALE = 8192.0f;        // 2^13
static constexpr float WSCALE = 1.0f / 8192.0f; // 2^-13

__device__ __forceinline__ uint32_t fbits(float f) {
    union { float f; uint32_t u; } v; v.f = f; return v.u;
}
__device__ __forceinline__ float asfloat(uint32_t u) {
    union { uint32_t u; float f; } v; v.u = u; return v.f;
}
__device__ __forceinline__ uint32_t bf16bits(float f) {
    union { bf16_t h; uint16_t u; } v; v.h = (bf16_t)f; return (uint32_t)v.u;
}

// ---- fp8 pair encode/decode (OCP e4m3fn). HW path on gfx950, manual fallback.
__device__ __forceinline__ uint32_t enc8(float v) {   // manual e4m3fn RNE
    const uint32_t s = (fbits(v) >> 24) & 0x80u;
    float m = fabsf(v) * 0x1p-120f;                   // map e4m3 grid onto fp32 bits
    uint32_t u = fbits(m);
    u += 0x7FFFFu + ((u >> 20) & 1u);                 // RNE at bit 20
    return s | ((u >> 20) & 0x7fu);
}
__device__ __forceinline__ uint32_t pack8(float a, float b) {
#if __has_builtin(__builtin_amdgcn_cvt_pk_fp8_f32)
    return (uint32_t)__builtin_amdgcn_cvt_pk_fp8_f32(a, b, 0, false) & 0xffffu;
#else
    return enc8(a) | (enc8(b) << 8);
#endif
}
__device__ __forceinline__ float2 unpack8(uint32_t u) {
#if __has_builtin(__builtin_amdgcn_cvt_pk_f32_fp8)
    f32x2v r = __builtin_amdgcn_cvt_pk_f32_fp8((int)(u & 0xffffu), false);
    return make_float2(r.x, r.y);
#else
    const float f0 = asfloat(((u & 0x80u) << 24) | ((u & 0x7fu) << 20)) * 0x1p120f;
    const float f1 = asfloat(((u & 0x8000u) << 16) | ((u & 0x7f00u) << 12)) * 0x1p120f;
    return make_float2(f0, f1);
#endif
}

// ---- prepass A: repack levels 8..15 of fp32 [T][L][F] -> fp8-pair ushorts,
// level-major [l-8][T] (2 MB). LDS-tiled transpose, coalesced writes.
__global__ __launch_bounds__(256)
void repack_enc8(const float2* __restrict__ src, uint16_t* __restrict__ dst) {
    __shared__ uint16_t ldsT[8 * 257];      // [l8][t_local], +1 pad
    const int tid = threadIdx.x;
    const int t0  = blockIdx.x * 256;       // 512 blocks x 256 t-entries
#pragma unroll
    for (int k = 0; k < 8; ++k) {
        const int j = k * 256 + tid;        // (t_local, l8): l8 fastest
        const int tl = j >> 3, l8 = j & 7;
        const float2 f = src[((size_t)(t0 + tl) << 4) + 8 + l8];
        ldsT[l8 * 257 + tl] = (uint16_t)pack8(f.x * FSCALE, f.y * FSCALE);
    }
    __syncthreads();
#pragma unroll
    for (int k = 0; k < 8; ++k)
        dst[((uint32_t)k << 17) + t0 + tid] = ldsT[k * 257 + tid];
}

// ---- prepass B: dense mini-grids, levels 0..7 (267 KB, fp8-pair ushorts).
__global__ __launch_bounds__(256)
void densify_enc(const float2* __restrict__ src, uint16_t* __restrict__ dst) {
    const int i = blockIdx.x * 256 + threadIdx.x;
    if (i >= NDALL) return;
    int lvl, W, off;
    if      (i <   289) { lvl = 0; W =  17; off = 0;     }
    else if (i <   914) { lvl = 1; W =  25; off = 289;   }
    else if (i <  2283) { lvl = 2; W =  37; off = 914;   }
    else if (i <  5308) { lvl = 3; W =  55; off = 2283;  }
    else if (i < 12032) { lvl = 4; W =  82; off = 5308;  }
    else if (i < 27161) { lvl = 5; W = 123; off = 12032; }
    else if (i < 61017) { lvl = 6; W = 184; off = 27161; }
    else                { lvl = 7; W = 275; off = 61017; }
    const int li = i - off;
    const uint32_t iy = (uint32_t)(li / W), ix = (uint32_t)(li % W);
    const uint32_t h = (ix ^ (iy * PRIME)) & HMASK;
    const float2 f = src[h * 16 + lvl];
    dst[i] = (uint16_t)pack8(f.x * FSCALE, f.y * FSCALE);
}

// ---- prepass C: overlapping pairs pair[i] = (d16[i], d16[i+1]) -> one dword
// load covers both x-corners of a dense bilerp (branch-free extract).
__global__ __launch_bounds__(256)
void pairify_enc(const uint16_t* __restrict__ d16, uint32_t* __restrict__ dst) {
    const int i = blockIdx.x * 256 + threadIdx.x;
    if (i >= NDALL) return;
    const uint32_t a = d16[i];
    const uint32_t b = (i + 1 < NDALL) ? d16[i + 1] : 0u;
    dst[i] = a | (b << 16);
}

// R13: wave-specialized encode, minimal implementation (R12 spilled via
// lambda-captured arrays -> alloca; here: straight-line, loads consumed
// immediately per level, nothing crosses a phase boundary in registers).
// Block = 64 points (4 tiles). Phase A: wave w computes levels 4w..4w+3 for
// all 64 points (lane = point) -> every gather path is WAVE-UNIFORM (R8 ran
// all 3 paths exec-masked = ~3x issue): w0 dense pairs lv0..3 (L1-hot 21KB),
// w1 dense pairs lv4..7 (L2), w2/w3 hashed (4 independent plain loads --
// R9 lesson). Feats -> double-buffered LDS feat[j][p] (stride 65); ONE
// barrier per iter between write and read (buffer alternation + barrier
// alignment makes WAR safe). Phase B: wave w MFMAs tile w exactly as R8.
__global__ __launch_bounds__(256, 2)
void fused_hash_mlp(const float* __restrict__ xin,
                    const uint16_t* __restrict__ tab8,   // hashed lv8..15, fp8
                    const uint32_t* __restrict__ dpair,  // dense lv0..7, pairs
                    const float* __restrict__ w0, const float* __restrict__ b0,
                    const float* __restrict__ w1, const float* __restrict__ b1,
                    const float* __restrict__ w2, const float* __restrict__ b2,
                    float* __restrict__ out,
                    int nGroups)
{
    __shared__ __align__(16) uint32_t feat[2][16 * 65];  // 8320 B
    __shared__ __align__(16) bf16_t lds[4 * 16 * 80];    // 10240 B per-wave tiles

    const int tid  = threadIdx.x;
    const int wib  = tid >> 6;      // phase A: level-quad lq; phase B: tile
    const int lane = tid & 63;
    const int q    = lane >> 4;
    const int n16  = lane & 15;
    const int lq   = wib;
    const int p    = lane;          // point index in phase A

    bf16_t* myLds = &lds[wib * (16 * 80)];

    // ---- weight B-fragments (fp32 -> bf16 once). Bw0 absorbs the 2^-13
    // feature un-scale (A carries feat*2^13).
    bf16x8 Bw0[4], Bw1[2][4], Bw2[2];
#pragma unroll
    for (int t = 0; t < 4; ++t)
#pragma unroll
        for (int j = 0; j < 8; ++j)
            Bw0[t][j] = (bf16_t)(w0[(q * 8 + j) * 64 + t * 16 + n16] * WSCALE);
#pragma unroll
    for (int c = 0; c < 2; ++c)
#pragma unroll
        for (int t = 0; t < 4; ++t)
#pragma unroll
            for (int j = 0; j < 8; ++j)
                Bw1[c][t][j] = (bf16_t)w1[(c * 32 + q * 8 + j) * 64 + t * 16 + n16];
#pragma unroll
    for (int c = 0; c < 2; ++c)
#pragma unroll
        for (int j = 0; j < 8; ++j)
            Bw2[c][j] = (n16 < 3) ? (bf16_t)w2[(c * 32 + q * 8 + j) * 3 + n16]
                                  : (bf16_t)0.0f;

    float bv0[4], bv1[4];
#pragma unroll
    for (int t = 0; t < 4; ++t) {
        bv0[t] = b0[t * 16 + n16];
        bv1[t] = b1[t * 16 + n16];
    }
    const float bv2 = (n16 < 3) ? b2[n16] : 0.0f;

    // phase-A scales (wave-uniform): levels 4*lq..4*lq+3; exact in fp32.
    const float sbA = 16.0f * ((lq == 0) ? 1.0f :
                               (lq == 1) ? 5.0625f :
                               (lq == 2) ? 25.62890625f :
                                           129.746337890625f);
    const float scA0 = sbA,          scA1 = sbA * 1.5f;
    const float scA2 = sbA * 2.25f,  scA3 = sbA * 3.375f;

    // hashed sub-table base for lq>=2 (wave-uniform)
    const uint32_t l8base = ((uint32_t)((lq >= 2 ? lq - 2 : 0) * 4)) << 17;

    const int stride = gridDim.x;

    for (int g = blockIdx.x, it = 0; g < nGroups; g += stride, ++it) {
        const int buf = it & 1;
        const float2 xy = ((const float2*)xin)[g * 64 + p];

        // ================= phase A: gather + bilerp + feat write ==========
        if (lq >= 2) {
            // hashed levels 8..15: per level 4 independent ushort loads
#pragma unroll
            for (int lv = 0; lv < 4; ++lv) {
                const float s = (lv == 0) ? scA0 : (lv == 1) ? scA1
                              : (lv == 2) ? scA2 : scA3;
                const float posx = xy.x * s, posy = xy.y * s;
                const float fx = floorf(posx), fy = floorf(posy);
                const uint32_t ix = (uint32_t)fx, iy = (uint32_t)fy;
                const uint32_t hy0 = iy * PRIME, hy1 = hy0 + PRIME;
                const uint32_t base = l8base + ((uint32_t)lv << 17);
                const uint32_t u00 = tab8[base + (( ix       ^ hy0) & HMASK)];
                const uint32_t u10 = tab8[base + (((ix + 1u) ^ hy0) & HMASK)];
                const uint32_t u01 = tab8[base + (( ix       ^ hy1) & HMASK)];
                const uint32_t u11 = tab8[base + (((ix + 1u) ^ hy1) & HMASK)];
                const float frx = posx - fx, fry = posy - fy;
                const float2 e00 = unpack8(u00);
                const float2 e10 = unpack8(u10);
                const float2 e01 = unpack8(u01);
                const float2 e11 = unpack8(u11);
                const float wx1 = frx, wx0 = 1.0f - frx, wy1 = fry, wy0 = 1.0f - fry;
                const float w00 = wx0 * wy0, w10 = wx1 * wy0;
                const float w01 = wx0 * wy1, w11 = wx1 * wy1;
                const float f0 = w00 * e00.x + w10 * e10.x + w01 * e01.x + w11 * e11.x;
                const float f1 = w00 * e00.y + w10 * e10.y + w01 * e01.y + w11 * e11.y;
                feat[buf][(lq * 4 + lv) * 65 + p] = bf16bits(f0) | (bf16bits(f1) << 16);
            }
        } else {
            // dense levels (pairs): per level 2 dword loads
#pragma unroll
            for (int lv = 0; lv < 4; ++lv) {
                const float s = (lv == 0) ? scA0 : (lv == 1) ? scA1
                              : (lv == 2) ? scA2 : scA3;
                const uint32_t W = (lq == 0)
                    ? ((lv == 0) ? 17u : (lv == 1) ? 25u : (lv == 2) ? 37u : 55u)
                    : ((lv == 0) ? 82u : (lv == 1) ? 123u : (lv == 2) ? 184u : 275u);
                const uint32_t O = (lq == 0)
                    ? ((lv == 0) ? 0u : (lv == 1) ? 289u : (lv == 2) ? 914u : 2283u)
                    : ((lv == 0) ? 5308u : (lv == 1) ? 12032u : (lv == 2) ? 27161u : 61017u);
                const float posx = xy.x * s, posy = xy.y * s;
                const float fx = floorf(posx), fy = floorf(posy);
                const uint32_t ix = (uint32_t)fx, iy = (uint32_t)fy;
                const uint32_t a = O + iy * W + ix;
                const uint32_t p0 = dpair[a];
                const uint32_t p1 = dpair[a + W];
                const float frx = posx - fx, fry = posy - fy;
                const float2 e00 = unpack8(p0 & 0xffffu);
                const float2 e10 = unpack8(p0 >> 16);
                const float2 e01 = unpack8(p1 & 0xffffu);
                const float2 e11 = unpack8(p1 >> 16);
                const float wx1 = frx, wx0 = 1.0f - frx, wy1 = fry, wy0 = 1.0f - fry;
                const float w00 = wx0 * wy0, w10 = wx1 * wy0;
                const float w01 = wx0 * wy1, w11 = wx1 * wy1;
                const float f0 = w00 * e00.x + w10 * e10.x + w01 * e01.x + w11 * e11.x;
                const float f1 = w00 * e00.y + w10 * e10.y + w01 * e01.y + w11 * e11.y;
                feat[buf][(lq * 4 + lv) * 65 + p] = bf16bits(f0) | (bf16bits(f1) << 16);
            }
        }

        __syncthreads();   // feat[buf] ready (only barrier per iteration)

        // ================= phase B: MLP on tile wib ========================
        union { uint32_t u[4]; bf16x8 v; } afu;
#pragma unroll
        for (int r = 0; r < 4; ++r)
            afu.u[r] = feat[buf][(q * 4 + r) * 65 + wib * 16 + n16];
        const bf16x8 af = afu.v;

        // ---- layer 0: [16x32] @ [32x64] + b0, relu ----
        f32x4 c0[4];
#pragma unroll
        for (int t = 0; t < 4; ++t) {
            f32x4 cc = { bv0[t], bv0[t], bv0[t], bv0[t] };
            c0[t] = __builtin_amdgcn_mfma_f32_16x16x32_bf16(af, Bw0[t], cc, 0, 0, 0);
        }
#pragma unroll
        for (int t = 0; t < 4; ++t)
#pragma unroll
            for (int r = 0; r < 4; ++r)
                myLds[(q * 4 + r) * 80 + t * 16 + n16] = (bf16_t)fmaxf(c0[t][r], 0.0f);
        bf16x8 A1[2];
#pragma unroll
        for (int c = 0; c < 2; ++c)
            A1[c] = *(const bf16x8*)&myLds[n16 * 80 + c * 32 + q * 8];

        // ---- layer 1: [16x64] @ [64x64] + b1, relu ----
        f32x4 c1[4];
#pragma unroll
        for (int t = 0; t < 4; ++t) {
            f32x4 cc = { bv1[t], bv1[t], bv1[t], bv1[t] };
            cc    = __builtin_amdgcn_mfma_f32_16x16x32_bf16(A1[0], Bw1[0][t], cc, 0, 0, 0);
            c1[t] = __builtin_amdgcn_mfma_f32_16x16x32_bf16(A1[1], Bw1[1][t], cc, 0, 0, 0);
        }
#pragma unroll
        for (int t = 0; t < 4; ++t)
#pragma unroll
            for (int r = 0; r < 4; ++r)
                myLds[(q * 4 + r) * 80 + t * 16 + n16] = (bf16_t)fmaxf(c1[t][r], 0.0f);
        bf16x8 A2[2];
#pragma unroll
        for (int c = 0; c < 2; ++c)
            A2[c] = *(const bf16x8*)&myLds[n16 * 80 + c * 32 + q * 8];

        // ---- layer 2: [16x64] @ [64x3 padded to 16] + b2 (no relu) ----
        f32x4 co = { bv2, bv2, bv2, bv2 };
        co = __builtin_amdgcn_mfma_f32_16x16x32_bf16(A2[0], Bw2[0], co, 0, 0, 0);
        co = __builtin_amdgcn_mfma_f32_16x16x32_bf16(A2[1], Bw2[1], co, 0, 0, 0);

        const int tile = g * 4 + wib;
        if (n16 < 3) {
#pragma unroll
            for (int r = 0; r < 4; ++r)
                out[(size_t)(tile * 16 + q * 4 + r) * 3 + n16] = co[r];
        }
    }
}

// ---- fallback (R2 known-good): direct fp32 gather, used only if ws too small
__global__ __launch_bounds__(256)
void fused_hash_mlp_fp32(const float* __restrict__ xin,
                         const float* __restrict__ enc,
                         const float* __restrict__ w0, const float* __restrict__ b0,
                         const float* __restrict__ w1, const float* __restrict__ b1,
                         const float* __restrict__ w2, const float* __restrict__ b2,
                         float* __restrict__ out,
                         int nGroups)
{
    __shared__ __align__(16) bf16_t lds[4 * 16 * 80];
    const int tid  = threadIdx.x;
    const int wib  = tid >> 6;
    const int lane = tid & 63;
    const int q    = lane >> 4;
    const int n16  = lane & 15;
    bf16_t* myLds = &lds[wib * (16 * 80)];

    bf16x8 Bw0[4], Bw1[2][4], Bw2[2];
#pragma unroll
    for (int t = 0; t < 4; ++t)
#pragma unroll
        for (int j = 0; j < 8; ++j)
            Bw0[t][j] = (bf16_t)w0[(q * 8 + j) * 64 + t * 16 + n16];
#pragma unroll
    for (int c = 0; c < 2; ++c)
#pragma unroll
        for (int t = 0; t < 4; ++t)
#pragma unroll
            for (int j = 0; j < 8; ++j)
                Bw1[c][t][j] = (bf16_t)w1[(c * 32 + q * 8 + j) * 64 + t * 16 + n16];
#pragma unroll
    for (int c = 0; c < 2; ++c)
#pragma unroll
        for (int j = 0; j < 8; ++j)
            Bw2[c][j] = (n16 < 3) ? (bf16_t)w2[(c * 32 + q * 8 + j) * 3 + n16]
                                  : (bf16_t)0.0f;

    float bv0[4], bv1[4];
#pragma unroll
    for (int t = 0; t < 4; ++t) { bv0[t] = b0[t * 16 + n16]; bv1[t] = b1[t * 16 + n16]; }
    const float bv2 = (n16 < 3) ? b2[n16] : 0.0f;

    const float sb = 16.0f * ((q == 0) ? 1.0f : (q == 1) ? 5.0625f :
                              (q == 2) ? 25.62890625f : 129.746337890625f);
    const float sc[4] = { sb, sb * 1.5f, sb * 2.25f, sb * 3.375f };
    const char* encB = (const char*)enc;
    const uint32_t lvBase = (uint32_t)q * 32u;

    for (int g = blockIdx.x; g < nGroups; g += gridDim.x) {
        const int tile = g * 4 + wib;
        const int p = tile * 16 + n16;
        const float2 xy = ((const float2*)xin)[p];
        const float px = xy.x, py = xy.y;

        bf16x8 af;
#pragma unroll
        for (int lv = 0; lv < 4; ++lv) {
            const float posx = px * sc[lv], posy = py * sc[lv];
            const float fx = floorf(posx), fy = floorf(posy);
            const float frx = posx - fx,  fry = posy - fy;
            const uint32_t ix = (uint32_t)fx, iy = (uint32_t)fy;
            const uint32_t hy0 = iy * PRIME, hy1 = hy0 + PRIME;
            const uint32_t i00 = ( ix       ^ hy0) & HMASK;
            const uint32_t i10 = ((ix + 1u) ^ hy0) & HMASK;
            const uint32_t i01 = ( ix       ^ hy1) & HMASK;
            const uint32_t i11 = ((ix + 1u) ^ hy1) & HMASK;
            const uint32_t off = lvBase + (uint32_t)lv * 8u;
            const float2 e00 = *(const float2*)(encB + (i00 * 128u + off));
            const float2 e10 = *(const float2*)(encB + (i10 * 128u + off));
            const float2 e01 = *(const float2*)(encB + (i01 * 128u + off));
            const float2 e11 = *(const float2*)(encB + (i11 * 128u + off));
            const float wx1 = frx, wx0 = 1.0f - frx, wy1 = fry, wy0 = 1.0f - fry;
            const float w00 = wx0 * wy0, w10 = wx1 * wy0, w01 = wx0 * wy1, w11 = wx1 * wy1;
            af[2 * lv]     = (bf16_t)(w00 * e00.x + w10 * e10.x + w01 * e01.x + w11 * e11.x);
            af[2 * lv + 1] = (bf16_t)(w00 * e00.y + w10 * e10.y + w01 * e01.y + w11 * e11.y);
        }

        f32x4 c0[4];
#pragma unroll
        for (int t = 0; t < 4; ++t) {
            f32x4 cc = { bv0[t], bv0[t], bv0[t], bv0[t] };
            c0[t] = __builtin_amdgcn_mfma_f32_16x16x32_bf16(af, Bw0[t], cc, 0, 0, 0);
        }
        __syncthreads();
#pragma unroll
        for (int t = 0; t < 4; ++t)
#pragma unroll
            for (int r = 0; r < 4; ++r)
                myLds[(q * 4 + r) * 80 + t * 16 + n16] = (bf16_t)fmaxf(c0[t][r], 0.0f);
        __syncthreads();
        bf16x8 A1[2];
#pragma unroll
        for (int c = 0; c < 2; ++c)
            A1[c] = *(const bf16x8*)&myLds[n16 * 80 + c * 32 + q * 8];

        f32x4 c1[4];
#pragma unroll
        for (int t = 0; t < 4; ++t) {
            f32x4 cc = { bv1[t], bv1[t], bv1[t], bv1[t] };
            cc    = __builtin_amdgcn_mfma_f32_16x16x32_bf16(A1[0], Bw1[0][t], cc, 0, 0, 0);
            c1[t] = __builtin_amdgcn_mfma_f32_16x16x32_bf16(A1[1], Bw1[1][t], cc, 0, 0, 0);
        }
        __syncthreads();
#pragma unroll
        for (int t = 0; t < 4; ++t)
#pragma unroll
            for (int r = 0; r < 4; ++r)
                myLds[(q * 4 + r) * 80 + t * 16 + n16] = (bf16_t)fmaxf(c1[t][r], 0.0f);
        __syncthreads();
        bf16x8 A2[2];
#pragma unroll
        for (int c = 0; c < 2; ++c)
            A2[c] = *(const bf16x8*)&myLds[n16 * 80 + c * 32 + q * 8];

        f32x4 co = { bv2, bv2, bv2, bv2 };
        co = __builtin_amdgcn_mfma_f32_16x16x32_bf16(A2[0], Bw2[0], co, 0, 0, 0);
        co = __builtin_amdgcn_mfma_f32_16x16x32_bf16(A2[1], Bw2[1], co, 0, 0, 0);
        if (n16 < 3) {
#pragma unroll
            for (int r = 0; r < 4; ++r)
                out[(size_t)(tile * 16 + q * 4 + r) * 3 + n16] = co[r];
        }
    }
}

extern "C" void kernel_launch(void* const* d_in, const int* in_sizes, int n_in,
                              void* d_out, int out_size, void* d_ws, size_t ws_size,
                              hipStream_t stream) {
    const float* x  = (const float*)d_in[0];
    const float* en = (const float*)d_in[1];
    const float* w0 = (const float*)d_in[2];
    const float* b0 = (const float*)d_in[3];
    const float* w1 = (const float*)d_in[4];
    const float* b1 = (const float*)d_in[5];
    const float* w2 = (const float*)d_in[6];
    const float* b2 = (const float*)d_in[7];
    float* out = (float*)d_out;

    const int N = in_sizes[0] / 2;      // 2^20 points
    const int nTiles = N / 16;          // 65536
    const int nGroups = nTiles / 4;     // 16384 (64-point groups)

    // ws layout: tab8 (2 MB) | dpair (NDALL u32, 534 KB) | d16 scratch (267 KB)
    const size_t wsNeeded = (size_t)TSIZE * 8 * 2 + (size_t)NDALL * 4 + (size_t)NDALL * 2;
    if (ws_size >= wsNeeded) {
        uint16_t* tab8  = (uint16_t*)d_ws;
        uint32_t* dpair = (uint32_t*)(tab8 + (size_t)TSIZE * 8);
        uint16_t* d16   = (uint16_t*)(dpair + NDALL);
        repack_enc8<<<TSIZE / 256, 256, 0, stream>>>((const float2*)en, tab8);
        densify_enc<<<(NDALL + 255) / 256, 256, 0, stream>>>((const float2*)en, d16);
        pairify_enc<<<(NDALL + 255) / 256, 256, 0, stream>>>(d16, dpair);
        int blocks = 2048;
        if (blocks > nGroups) blocks = nGroups;
        fused_hash_mlp<<<blocks, 256, 0, stream>>>(x, tab8, dpair,
                                                   w0, b0, w1, b1, w2, b2, out, nGroups);
    } else {
        int blocks = 2048;
        if (blocks > nGroups) blocks = nGroups;
        fused_hash_mlp_fp32<<<blocks, 256, 0, stream>>>(x, en, w0, b0, w1, b1, w2, b2, out, nGroups);
    }
}